// Round 1
// baseline (73.952 us; speedup 1.0000x reference)
//
#include <hip/hip_runtime.h>
#include <stdint.h>

#define NP 4096          // power-of-two sort size >= N
#define THREADS 512
#define MAXF 50

__global__ __launch_bounds__(THREADS) void randbox_kernel(
    const float* __restrict__ rb,      // [B, N, 4]
    const float* __restrict__ scores,  // [B, N]
    const int*   __restrict__ numf,    // [B]
    const int*   __restrict__ hw,      // [B, 2]  (H, W)
    float* __restrict__ out,           // boxes [B,50,4] | mask [B,50] | count [B]
    int N, int B)
{
    __shared__ unsigned long long keys[NP];
    __shared__ float4 boxes[NP];   // scaled boxes by original index

    const int b   = blockIdx.x;
    const int tid = threadIdx.x;
    const float H = (float)hw[b * 2 + 0];
    const float W = (float)hw[b * 2 + 1];
    const int   nf = numf[b];

    // ---- Phase 1: load, order corners, scale, validity, build sort keys ----
    for (int i = tid; i < NP; i += THREADS) {
        unsigned long long key;
        if (i < N) {
            float4 r = ((const float4*)rb)[(size_t)b * N + i];
            float x1 = fminf(r.x, r.z) * W;
            float x2 = fmaxf(r.x, r.z) * W;
            float y1 = fminf(r.y, r.w) * H;
            float y2 = fmaxf(r.y, r.w) * H;
            bool valid = ((y2 - y1) > 0.1f * H) && ((x2 - x1) > 0.1f * W);
            boxes[i] = make_float4(x1, y1, x2, y2);
            // score in [0,1): bit pattern is order-monotonic for non-negative f32.
            // +1 so valid score 0.0 still beats invalid (key 0).
            unsigned int sk = valid ? (__float_as_uint(scores[(size_t)b * N + i]) + 1u) : 0u;
            // low bits (NP-1-i): descending sort => smaller original index first
            // on score ties, matching jnp.argsort's stable order.
            key = ((unsigned long long)sk << 32) | (unsigned int)(NP - 1 - i);
        } else {
            key = (unsigned int)(NP - 1 - i);   // padding, sorts last
        }
        keys[i] = key;
    }
    __syncthreads();

    // ---- Phase 2: bitonic sort, descending ----
    for (int k = 2; k <= NP; k <<= 1) {
        for (int j = k >> 1; j > 0; j >>= 1) {
            for (int t = tid; t < NP / 2; t += THREADS) {
                int i   = ((t & ~(j - 1)) << 1) | (t & (j - 1));
                int ixj = i | j;
                unsigned long long a = keys[i];
                unsigned long long c = keys[ixj];
                bool desc = ((i & k) == 0);
                if (desc ? (a < c) : (a > c)) { keys[i] = c; keys[ixj] = a; }
            }
            __syncthreads();
        }
    }

    // ---- Phase 3: greedy NMS by wave 0, early-stop at nf kept ----
    if (tid < 64) {
        const int lane = tid;
        const size_t box_base = (size_t)b * MAXF * 4;
        const size_t mask_off = (size_t)B * MAXF * 4;
        const size_t cnt_off  = mask_off + (size_t)B * MAXF;

        float kx1 = 0.f, ky1 = 0.f, kx2 = 0.f, ky2 = 0.f, karea = 0.f;
        int nk = 0;
        for (int r = 0; r < NP; ++r) {
            unsigned long long kv = keys[r];             // uniform -> LDS broadcast
            if ((unsigned int)(kv >> 32) == 0u) break;   // no more valid boxes
            int idx = NP - 1 - (int)(kv & 0xFFFFFFFFu);
            float4 c = boxes[idx];                       // uniform -> broadcast
            float carea = (c.z - c.x) * (c.w - c.y);
            // lane k (< nk) checks candidate vs its kept box
            float xx1 = fmaxf(kx1, c.x);
            float yy1 = fmaxf(ky1, c.y);
            float xx2 = fminf(kx2, c.z);
            float yy2 = fminf(ky2, c.w);
            float inter = fmaxf(xx2 - xx1, 0.0f) * fmaxf(yy2 - yy1, 0.0f);
            float iou   = inter / ((karea + carea) - inter + 1e-9f);
            bool sup = (lane < nk) && (iou > 0.7f);
            if (__ballot(sup) == 0ULL) {
                if (lane == nk) {
                    kx1 = c.x; ky1 = c.y; kx2 = c.z; ky2 = c.w; karea = carea;
                    *(float4*)(out + box_base + (size_t)nk * 4) = c;  // emit kept box
                }
                ++nk;
                if (nk >= nf) break;    // count clamps at nf; rest irrelevant
            }
        }

        // ---- Phase 4: pad outputs (zero unused slots, mask, count) ----
        if (lane < MAXF) {
            if (lane >= nk)
                *(float4*)(out + box_base + (size_t)lane * 4) = make_float4(0.f, 0.f, 0.f, 0.f);
            out[mask_off + (size_t)b * MAXF + lane] = (lane < nk) ? 1.0f : 0.0f;
        }
        if (lane == 0)
            out[cnt_off + b] = (float)nk;
    }
}

extern "C" void kernel_launch(void* const* d_in, const int* in_sizes, int n_in,
                              void* d_out, int out_size, void* d_ws, size_t ws_size,
                              hipStream_t stream) {
    const float* rb     = (const float*)d_in[0];
    const float* scores = (const float*)d_in[1];
    const int*   numf   = (const int*)d_in[2];
    const int*   hw     = (const int*)d_in[3];
    const int B = in_sizes[2];              // 8
    const int N = in_sizes[1] / B;          // 4000
    randbox_kernel<<<B, THREADS, 0, stream>>>(rb, scores, numf, hw,
                                              (float*)d_out, N, B);
}

// Round 2
// 35.623 us; speedup vs baseline: 2.0760x; 2.0760x over previous
//
#include <hip/hip_runtime.h>
#include <stdint.h>

#define THREADS 256
#define MAXF 50
#define NBUCK 1024
#define KTGT 192          // target candidates per group (>= 49 kept + slack)
#define CANDMAX 256
#define NMAX 4000

__global__ __launch_bounds__(THREADS) void randbox_kernel(
    const float* __restrict__ rb,      // [B, N, 4]
    const float* __restrict__ scores,  // [B, N]
    const int*   __restrict__ numf,    // [B]
    const int*   __restrict__ hw,      // [B, 2]  (H, W)
    float* __restrict__ out,           // boxes [B,50,4] | mask [B,50] | count [B]
    int N, int B)
{
    __shared__ float4 boxesLds[NMAX];          // scaled boxes by original index
    __shared__ unsigned int skArr[NMAX];       // score key (bits+1), 0 = invalid
    __shared__ unsigned int hist[NBUCK];
    __shared__ unsigned int S[NBUCK];          // suffix counts S[t] = sum_{u>=t} hist[u]
    __shared__ unsigned long long candKey[CANDMAX];
    __shared__ float4 candBox[CANDMAX + 4];
    __shared__ unsigned int candCnt;
    __shared__ int tlo_s, thi_s, done_s;

    const int b    = blockIdx.x;
    const int tid  = threadIdx.x;
    const int lane = tid & 63;
    const float H = (float)hw[b * 2 + 0];
    const float W = (float)hw[b * 2 + 1];
    const int  nf = numf[b];
    const int  NN = (N < NMAX) ? N : NMAX;

    const size_t box_base = (size_t)b * MAXF * 4;
    const size_t mask_off = (size_t)B * MAXF * 4;
    const size_t cnt_off  = mask_off + (size_t)B * MAXF;

    // ---- Phase 1: load, order corners, scale, validity, histogram ----
    for (int i = tid; i < NBUCK; i += THREADS) hist[i] = 0;
    if (tid == 0) thi_s = NBUCK;
    __syncthreads();

    for (int i = tid; i < NN; i += THREADS) {
        float4 r = ((const float4*)rb)[(size_t)b * N + i];
        float x1 = fminf(r.x, r.z) * W;
        float x2 = fmaxf(r.x, r.z) * W;
        float y1 = fminf(r.y, r.w) * H;
        float y2 = fmaxf(r.y, r.w) * H;
        bool valid = ((y2 - y1) > 0.1f * H) && ((x2 - x1) > 0.1f * W);
        boxesLds[i] = make_float4(x1, y1, x2, y2);
        float s = scores[(size_t)b * N + i];
        unsigned int sk = 0u;
        if (valid) {
            sk = __float_as_uint(s) + 1u;   // monotone for s >= 0; 0 reserved
            int bk = (int)(s * (float)NBUCK);
            if (bk > NBUCK - 1) bk = NBUCK - 1;
            atomicAdd(&hist[bk], 1u);
        }
        skArr[i] = sk;
    }
    __syncthreads();

    // ---- Phase 2: suffix sums over buckets (wave 0, shuffle scan) ----
    if (tid < 64) {
        unsigned int loc[16];
        unsigned int sum = 0;
        int base = lane * 16;
        #pragma unroll
        for (int u = 15; u >= 0; --u) { sum += hist[base + u]; loc[u] = sum; }
        unsigned int tot = sum, inc = sum;
        #pragma unroll
        for (int d = 1; d < 64; d <<= 1) {
            unsigned int o = __shfl_down(inc, d, 64);
            if (lane + d < 64) inc += o;
        }
        unsigned int above = inc - tot;       // suffix of later chunks
        #pragma unroll
        for (int u = 0; u < 16; ++u) S[base + u] = loc[u] + above;
    }
    __syncthreads();

    // ---- Phase 3: group loop — select bucket range, compact, sort, NMS ----
    float kx1 = 0.f, ky1 = 0.f, kx2 = 0.f, ky2 = 0.f, karea = 0.f;
    int nk = 0;

    while (true) {
        // wave 0: largest t_lo with S[t_lo] - S[t_hi] >= KTGT (else 0)
        if (tid < 64) {
            int t_hi = thi_s;
            unsigned int X = ((t_hi == NBUCK) ? 0u : S[t_hi]) + KTGT;
            int best = -1;
            for (int t = lane; t < NBUCK; t += 64)
                if (S[t] >= X) best = (t > best) ? t : best;
            #pragma unroll
            for (int d = 1; d < 64; d <<= 1) {
                int o = __shfl_xor(best, d, 64);
                best = (o > best) ? o : best;
            }
            if (lane == 0) { tlo_s = (best < 0) ? 0 : best; candCnt = 0; }
        }
        candKey[tid] = 0ULL;       // pad for the pow2 sort
        __syncthreads();

        // all threads: compact candidates in [t_lo, t_hi)
        {
            const int t_lo = tlo_s, t_hi = thi_s;
            for (int i = tid; i < NN; i += THREADS) {
                unsigned int sk = skArr[i];
                if (sk) {
                    float s = __uint_as_float(sk - 1u);
                    int bk = (int)(s * (float)NBUCK);
                    if (bk > NBUCK - 1) bk = NBUCK - 1;
                    if (bk >= t_lo && bk < t_hi) {
                        unsigned int pos = atomicAdd(&candCnt, 1u);
                        if (pos < CANDMAX)
                            candKey[pos] = ((unsigned long long)sk << 32)
                                         | (unsigned int)(4095 - i);
                    }
                }
            }
        }
        __syncthreads();

        // wave 0: in-register bitonic sort of 256 keys (4/lane), then NMS
        if (tid < 64) {
            int C = (int)candCnt; if (C > CANDMAX) C = CANDMAX;

            unsigned long long v[4];
            #pragma unroll
            for (int r2 = 0; r2 < 4; ++r2) v[r2] = candKey[(lane << 2) | r2];

            for (int k = 2; k <= 256; k <<= 1) {
                for (int j = k >> 1; j > 0; j >>= 1) {
                    if (j >= 4) {
                        int lj = j >> 2;
                        #pragma unroll
                        for (int r2 = 0; r2 < 4; ++r2) {
                            unsigned long long o = __shfl_xor(v[r2], lj, 64);
                            int e = (lane << 2) | r2;
                            bool up = ((e & k) == 0);          // descending region
                            bool lower = ((lane & lj) == 0);   // j-bit of e clear
                            unsigned long long mx = (v[r2] > o) ? v[r2] : o;
                            unsigned long long mn = (v[r2] > o) ? o : v[r2];
                            v[r2] = (up == lower) ? mx : mn;
                        }
                    } else {
                        #pragma unroll
                        for (int r2 = 0; r2 < 4; ++r2) {
                            if ((r2 & j) == 0) {
                                int e = (lane << 2) | r2;
                                bool up = ((e & k) == 0);
                                unsigned long long a = v[r2], c2 = v[r2 | j];
                                if (up ? (a < c2) : (a > c2)) { v[r2] = c2; v[r2 | j] = a; }
                            }
                        }
                    }
                }
            }

            // scatter sorted candidate boxes to contiguous LDS
            #pragma unroll
            for (int r2 = 0; r2 < 4; ++r2) {
                int e = (lane << 2) | r2;
                if ((unsigned int)(v[r2] >> 32) != 0u) {
                    int idx = 4095 - (int)(v[r2] & 0xFFFFFFFFu);
                    candBox[e] = boxesLds[idx];
                }
            }

            // greedy NMS, kept boxes one-per-lane, prefetch next candidate
            if (C > 0 && nk < nf) {
                float4 c = candBox[0];
                for (int r = 0; r < C; ) {
                    float4 nx = candBox[r + 1];   // prefetch (pad slot exists)
                    float carea = (c.z - c.x) * (c.w - c.y);
                    float xx1 = fmaxf(kx1, c.x);
                    float yy1 = fmaxf(ky1, c.y);
                    float xx2 = fminf(kx2, c.z);
                    float yy2 = fminf(ky2, c.w);
                    float inter = fmaxf(xx2 - xx1, 0.f) * fmaxf(yy2 - yy1, 0.f);
                    float iou = inter / ((karea + carea) - inter + 1e-9f);
                    bool sup = (lane < nk) && (iou > 0.7f);
                    if (__ballot(sup) == 0ULL) {
                        if (lane == nk) {
                            kx1 = c.x; ky1 = c.y; kx2 = c.z; ky2 = c.w; karea = carea;
                            *(float4*)(out + box_base + (size_t)nk * 4) = c;
                        }
                        ++nk;
                        if (nk >= nf) break;
                    }
                    c = nx; ++r;
                }
            }

            if (lane == 0) {
                done_s = (nk >= nf) || (tlo_s == 0);
                thi_s = tlo_s;
            }
        }
        __syncthreads();
        if (done_s) break;
    }

    // ---- Phase 4: pad outputs (zero unused slots, mask, count) ----
    if (tid < 64) {
        if (lane < MAXF) {
            if (lane >= nk)
                *(float4*)(out + box_base + (size_t)lane * 4) =
                    make_float4(0.f, 0.f, 0.f, 0.f);
            out[mask_off + (size_t)b * MAXF + lane] = (lane < nk) ? 1.0f : 0.0f;
        }
        if (lane == 0)
            out[cnt_off + b] = (float)nk;
    }
}

extern "C" void kernel_launch(void* const* d_in, const int* in_sizes, int n_in,
                              void* d_out, int out_size, void* d_ws, size_t ws_size,
                              hipStream_t stream) {
    const float* rb     = (const float*)d_in[0];
    const float* scores = (const float*)d_in[1];
    const int*   numf   = (const int*)d_in[2];
    const int*   hw     = (const int*)d_in[3];
    const int B = in_sizes[2];              // 8
    const int N = in_sizes[1] / B;          // 4000
    randbox_kernel<<<B, THREADS, 0, stream>>>(rb, scores, numf, hw,
                                              (float*)d_out, N, B);
}

// Round 3
// 24.046 us; speedup vs baseline: 3.0754x; 1.4814x over previous
//
#include <hip/hip_runtime.h>
#include <stdint.h>

#define THREADS 1024
#define MAXF 50
#define NBUCK 1024
#define KTGT 96           // target candidates per group (>= 49 kept + slack)
#define CANDMAX 128
#define NMAX 4000

__global__ __launch_bounds__(THREADS) void randbox_kernel(
    const float* __restrict__ rb,      // [B, N, 4]
    const float* __restrict__ scores,  // [B, N]
    const int*   __restrict__ numf,    // [B]
    const int*   __restrict__ hw,      // [B, 2]  (H, W)
    float* __restrict__ out,           // boxes [B,50,4] | mask [B,50] | count [B]
    int N, int B)
{
    __shared__ float4 boxesLds[NMAX];          // scaled boxes by original index
    __shared__ unsigned int skArr[NMAX];       // score key (bits+1), 0 = invalid
    __shared__ unsigned int hist[NBUCK];
    __shared__ unsigned int S[NBUCK];          // suffix counts S[t] = sum_{u>=t} hist[u]
    __shared__ unsigned long long candKey[CANDMAX];
    __shared__ float4 candBox[CANDMAX + 4];
    __shared__ unsigned int candCnt;
    __shared__ int tlo_s, thi_s, done_s;

    const int b    = blockIdx.x;
    const int tid  = threadIdx.x;
    const int lane = tid & 63;
    const float H = (float)hw[b * 2 + 0];
    const float W = (float)hw[b * 2 + 1];
    const int  nf = numf[b];
    const int  NN = (N < NMAX) ? N : NMAX;

    const size_t box_base = (size_t)b * MAXF * 4;
    const size_t mask_off = (size_t)B * MAXF * 4;
    const size_t cnt_off  = mask_off + (size_t)B * MAXF;

    // ---- Phase 1: load, order corners, scale, validity, histogram ----
    for (int i = tid; i < NBUCK; i += THREADS) hist[i] = 0;
    if (tid == 0) thi_s = NBUCK;
    __syncthreads();

    for (int i = tid; i < NN; i += THREADS) {
        float4 r = ((const float4*)rb)[(size_t)b * N + i];
        float x1 = fminf(r.x, r.z) * W;
        float x2 = fmaxf(r.x, r.z) * W;
        float y1 = fminf(r.y, r.w) * H;
        float y2 = fmaxf(r.y, r.w) * H;
        bool valid = ((y2 - y1) > 0.1f * H) && ((x2 - x1) > 0.1f * W);
        boxesLds[i] = make_float4(x1, y1, x2, y2);
        float s = scores[(size_t)b * N + i];
        unsigned int sk = 0u;
        if (valid) {
            sk = __float_as_uint(s) + 1u;   // monotone for s >= 0; 0 reserved
            int bk = (int)(s * (float)NBUCK);
            if (bk > NBUCK - 1) bk = NBUCK - 1;
            atomicAdd(&hist[bk], 1u);
        }
        skArr[i] = sk;
    }
    __syncthreads();

    // ---- Phase 2: suffix sums over buckets (wave 0, shuffle scan) ----
    if (tid < 64) {
        unsigned int loc[16];
        unsigned int sum = 0;
        int base = lane * 16;
        #pragma unroll
        for (int u = 15; u >= 0; --u) { sum += hist[base + u]; loc[u] = sum; }
        unsigned int tot = sum, inc = sum;
        #pragma unroll
        for (int d = 1; d < 64; d <<= 1) {
            unsigned int o = __shfl_down(inc, d, 64);
            if (lane + d < 64) inc += o;
        }
        unsigned int above = inc - tot;       // suffix of later chunks
        #pragma unroll
        for (int u = 0; u < 16; ++u) S[base + u] = loc[u] + above;
    }
    __syncthreads();

    // ---- Phase 3: group loop — select bucket range, compact, sort, NMS ----
    float kx1 = 0.f, ky1 = 0.f, kx2 = 0.f, ky2 = 0.f, karea = 0.f;
    int nk = 0;

    while (true) {
        // wave 0: largest t_lo with S[t_lo] - S[t_hi] >= KTGT (else 0)
        if (tid < 64) {
            int t_hi = thi_s;
            unsigned int X = ((t_hi == NBUCK) ? 0u : S[t_hi]) + KTGT;
            int best = -1;
            for (int t = lane; t < NBUCK; t += 64)
                if (S[t] >= X) best = (t > best) ? t : best;
            #pragma unroll
            for (int d = 1; d < 64; d <<= 1) {
                int o = __shfl_xor(best, d, 64);
                best = (o > best) ? o : best;
            }
            if (lane == 0) { tlo_s = (best < 0) ? 0 : best; candCnt = 0; }
        }
        if (tid < CANDMAX) candKey[tid] = 0ULL;   // pad for the pow2 sort
        __syncthreads();

        // all threads: compact candidates in [t_lo, t_hi)
        {
            const int t_lo = tlo_s, t_hi = thi_s;
            for (int i = tid; i < NN; i += THREADS) {
                unsigned int sk = skArr[i];
                if (sk) {
                    float s = __uint_as_float(sk - 1u);
                    int bk = (int)(s * (float)NBUCK);
                    if (bk > NBUCK - 1) bk = NBUCK - 1;
                    if (bk >= t_lo && bk < t_hi) {
                        unsigned int pos = atomicAdd(&candCnt, 1u);
                        if (pos < CANDMAX)
                            candKey[pos] = ((unsigned long long)sk << 32)
                                         | (unsigned int)(4095 - i);
                    }
                }
            }
        }
        __syncthreads();

        // wave 0: in-register bitonic sort of 128 keys (2/lane), then NMS
        if (tid < 64) {
            int C = (int)candCnt; if (C > CANDMAX) C = CANDMAX;

            unsigned long long v[2];
            v[0] = candKey[lane << 1];
            v[1] = candKey[(lane << 1) | 1];

            for (int k = 2; k <= CANDMAX; k <<= 1) {
                for (int j = k >> 1; j > 0; j >>= 1) {
                    if (j >= 2) {
                        int lj = j >> 1;
                        #pragma unroll
                        for (int r2 = 0; r2 < 2; ++r2) {
                            unsigned long long o = __shfl_xor(v[r2], lj, 64);
                            int e = (lane << 1) | r2;
                            bool up = ((e & k) == 0);          // descending region
                            bool lower = ((lane & lj) == 0);   // j-bit of e clear
                            unsigned long long mx = (v[r2] > o) ? v[r2] : o;
                            unsigned long long mn = (v[r2] > o) ? o : v[r2];
                            v[r2] = (up == lower) ? mx : mn;
                        }
                    } else {
                        int e0 = (lane << 1);
                        bool up = ((e0 & k) == 0);
                        unsigned long long a = v[0], c2 = v[1];
                        if (up ? (a < c2) : (a > c2)) { v[0] = c2; v[1] = a; }
                    }
                }
            }

            // scatter sorted candidate boxes to contiguous LDS
            #pragma unroll
            for (int r2 = 0; r2 < 2; ++r2) {
                int e = (lane << 1) | r2;
                if ((unsigned int)(v[r2] >> 32) != 0u) {
                    int idx = 4095 - (int)(v[r2] & 0xFFFFFFFFu);
                    candBox[e] = boxesLds[idx];
                }
            }

            // greedy NMS, kept boxes one-per-lane, prefetch next candidate
            if (C > 0 && nk < nf) {
                float4 c = candBox[0];
                for (int r = 0; r < C; ) {
                    float4 nx = candBox[r + 1];   // prefetch (pad slot exists)
                    float carea = (c.z - c.x) * (c.w - c.y);
                    float xx1 = fmaxf(kx1, c.x);
                    float yy1 = fmaxf(ky1, c.y);
                    float xx2 = fminf(kx2, c.z);
                    float yy2 = fminf(ky2, c.w);
                    float inter = fmaxf(xx2 - xx1, 0.f) * fmaxf(yy2 - yy1, 0.f);
                    float iou = inter / ((karea + carea) - inter + 1e-9f);
                    bool sup = (lane < nk) && (iou > 0.7f);
                    if (__ballot(sup) == 0ULL) {
                        if (lane == nk) {
                            kx1 = c.x; ky1 = c.y; kx2 = c.z; ky2 = c.w; karea = carea;
                            *(float4*)(out + box_base + (size_t)nk * 4) = c;
                        }
                        ++nk;
                        if (nk >= nf) break;
                    }
                    c = nx; ++r;
                }
            }

            if (lane == 0) {
                done_s = (nk >= nf) || (tlo_s == 0);
                thi_s = tlo_s;
            }
        }
        __syncthreads();
        if (done_s) break;
    }

    // ---- Phase 4: pad outputs (zero unused slots, mask, count) ----
    if (tid < 64) {
        if (lane < MAXF) {
            if (lane >= nk)
                *(float4*)(out + box_base + (size_t)lane * 4) =
                    make_float4(0.f, 0.f, 0.f, 0.f);
            out[mask_off + (size_t)b * MAXF + lane] = (lane < nk) ? 1.0f : 0.0f;
        }
        if (lane == 0)
            out[cnt_off + b] = (float)nk;
    }
}

extern "C" void kernel_launch(void* const* d_in, const int* in_sizes, int n_in,
                              void* d_out, int out_size, void* d_ws, size_t ws_size,
                              hipStream_t stream) {
    const float* rb     = (const float*)d_in[0];
    const float* scores = (const float*)d_in[1];
    const int*   numf   = (const int*)d_in[2];
    const int*   hw     = (const int*)d_in[3];
    const int B = in_sizes[2];              // 8
    const int N = in_sizes[1] / B;          // 4000
    randbox_kernel<<<B, THREADS, 0, stream>>>(rb, scores, numf, hw,
                                              (float*)d_out, N, B);
}

// Round 4
// 21.229 us; speedup vs baseline: 3.4836x; 1.1327x over previous
//
#include <hip/hip_runtime.h>
#include <stdint.h>

#define THREADS 1024
#define MAXF 50
#define PREMAX 256
#define CUT 0.965f
#define NMSTHR 0.7f

typedef unsigned long long u64;

__global__ __launch_bounds__(THREADS) void randbox_kernel(
    const float* __restrict__ rb,      // [B, N, 4]
    const float* __restrict__ scores,  // [B, N]
    const int*   __restrict__ numf,    // [B]
    const int*   __restrict__ hw,      // [B, 2] (H, W)
    float* __restrict__ out,           // boxes [B,50,4] | mask [B,50] | count [B]
    int N, int B)
{
    __shared__ u64 preKey[PREMAX];
    __shared__ float4 preBox[PREMAX];
    __shared__ unsigned short posMap[4096];
    __shared__ float4 candBox[PREMAX + 4];
    __shared__ u64 adjLds[128][2];
    __shared__ u64 consumed[64];
    __shared__ unsigned int preCnt;
    __shared__ int status_s;

    const int b = blockIdx.x, tid = threadIdx.x, lane = tid & 63, wid = tid >> 6;
    const float H = (float)hw[b * 2 + 0];
    const float W = (float)hw[b * 2 + 1];
    const int nf = numf[b];
    const int NN = (N < 4096) ? N : 4096;
    const float4* rb4 = (const float4*)rb + (size_t)b * N;
    const float*  sc  = scores + (size_t)b * N;

    const size_t box_base = (size_t)b * MAXF * 4;
    const size_t mask_off = (size_t)B * MAXF * 4;
    const size_t cnt_off  = mask_off + (size_t)B * MAXF;

    // ---- Phase 1: load, order corners, scale, validity, prefilter-push ----
    for (int i = tid; i < PREMAX; i += THREADS) preKey[i] = 0ULL;
    if (tid == 0) { preCnt = 0; status_s = 0; }
    __syncthreads();

    for (int i = tid; i < NN; i += THREADS) {
        float4 r = rb4[i];
        float x1 = fminf(r.x, r.z) * W;
        float x2 = fmaxf(r.x, r.z) * W;
        float y1 = fminf(r.y, r.w) * H;
        float y2 = fmaxf(r.y, r.w) * H;
        bool valid = ((y2 - y1) > 0.1f * H) && ((x2 - x1) > 0.1f * W);
        float s = sc[i];
        if (valid && s > CUT) {
            unsigned int pos = atomicAdd(&preCnt, 1u);
            if (pos < PREMAX) {
                preKey[pos] = ((u64)(__float_as_uint(s) + 1u) << 32)
                            | (unsigned int)(4095 - i);
                preBox[pos] = make_float4(x1, y1, x2, y2);
                posMap[i] = (unsigned short)pos;
            }
        }
    }
    __syncthreads();

    const int cnt = (int)preCnt;
    auto maskLE = [](int m) -> u64 {
        if (m < 0) return 0ULL;
        if (m >= 63) return ~0ULL;
        return (1ULL << (m + 1)) - 1ULL;
    };

    if (cnt <= 128) {
        // ---- Path A (typical): sort128 in wave-0 regs, parallel-adj NMS ----
        if (wid == 0) {
            u64 v[2];
            v[0] = preKey[lane << 1];
            v[1] = preKey[(lane << 1) | 1];
            for (int k = 2; k <= 128; k <<= 1) {
                for (int j = k >> 1; j > 0; j >>= 1) {
                    if (j >= 2) {
                        int lj = j >> 1;
                        #pragma unroll
                        for (int r2 = 0; r2 < 2; ++r2) {
                            u64 o = __shfl_xor(v[r2], lj, 64);
                            int e = (lane << 1) | r2;
                            bool up = ((e & k) == 0);
                            bool lower = ((lane & lj) == 0);
                            u64 mx = (v[r2] > o) ? v[r2] : o;
                            u64 mn = (v[r2] > o) ? o : v[r2];
                            v[r2] = (up == lower) ? mx : mn;
                        }
                    } else {
                        int e0 = (lane << 1);
                        bool up = ((e0 & k) == 0);
                        u64 a = v[0], c2 = v[1];
                        if (up ? (a < c2) : (a > c2)) { v[0] = c2; v[1] = a; }
                    }
                }
            }
            #pragma unroll
            for (int r2 = 0; r2 < 2; ++r2) {
                int e = (lane << 1) | r2;
                if ((unsigned int)(v[r2] >> 32) != 0u) {
                    int idx = 4095 - (int)(v[r2] & 0xFFFFFFFFu);
                    candBox[e] = preBox[posMap[idx]];
                }
            }
        }
        __syncthreads();

        // adjacency: 16 waves, ballot one 64-bit word per (row, word)
        for (int i = wid; i < cnt; i += 16) {
            float4 bi = candBox[i];
            float ai = (bi.z - bi.x) * (bi.w - bi.y);
            #pragma unroll
            for (int w2 = 0; w2 < 2; ++w2) {
                int jj = (w2 << 6) | lane;
                bool pred = false;
                if (jj > i && jj < cnt) {
                    float4 bj = candBox[jj];
                    float aj = (bj.z - bj.x) * (bj.w - bj.y);
                    float xx1 = fmaxf(bi.x, bj.x);
                    float yy1 = fmaxf(bi.y, bj.y);
                    float xx2 = fminf(bi.z, bj.z);
                    float yy2 = fminf(bi.w, bj.w);
                    float inter = fmaxf(xx2 - xx1, 0.f) * fmaxf(yy2 - yy1, 0.f);
                    pred = inter / ((ai + aj) - inter + 1e-9f) > NMSTHR;
                }
                u64 m = __ballot(pred);
                if (lane == 0) adjLds[i][w2] = m;
            }
        }
        __syncthreads();

        if (wid == 0) {
            u64 alive0 = 0, alive1 = 0;
            if (cnt >= 64) alive0 = ~0ULL;
            else if (cnt > 0) alive0 = (1ULL << cnt) - 1ULL;
            if (cnt >= 128) alive1 = ~0ULL;
            else if (cnt > 64) alive1 = (1ULL << (cnt - 64)) - 1ULL;

            int nk = 0, last = -1;
            if (cnt > 0 && nf > 0) {
                u64 n0 = adjLds[0][0], n1 = adjLds[0][1];
                for (int i = 0; i < cnt; ++i) {
                    u64 c0 = n0, c1 = n1;
                    if (i + 1 < cnt) { n0 = adjLds[i + 1][0]; n1 = adjLds[i + 1][1]; }
                    bool kept = (i < 64) ? ((alive0 >> i) & 1ULL)
                                         : ((alive1 >> (i - 64)) & 1ULL);
                    if (kept) {
                        ++nk; last = i;
                        if (nk >= nf) break;
                        alive0 &= ~c0; alive1 &= ~c1;
                    }
                }
            }
            alive0 &= maskLE(last);
            alive1 &= maskLE(last - 64);

            // epilogue: zero-fill + mask, then popcount-rank parallel emit
            if (lane < MAXF) {
                if (lane >= nk)
                    *(float4*)(out + box_base + (size_t)lane * 4) =
                        make_float4(0.f, 0.f, 0.f, 0.f);
                out[mask_off + (size_t)b * MAXF + lane] = (lane < nk) ? 1.0f : 0.0f;
            }
            u64 below = (lane == 0) ? 0ULL : ((1ULL << lane) - 1ULL);
            if ((alive0 >> lane) & 1ULL) {
                int rank = __popcll(alive0 & below);
                if (rank < nf)
                    *(float4*)(out + box_base + (size_t)rank * 4) = candBox[lane];
            }
            if ((alive1 >> lane) & 1ULL) {
                int rank = __popcll(alive0) + __popcll(alive1 & below);
                if (rank < nf)
                    *(float4*)(out + box_base + (size_t)rank * 4) = candBox[64 + lane];
            }
            if (lane == 0) {
                out[cnt_off + b] = (float)nk;
                status_s = (nk < nf) ? 1 : 0;
            }
        }
        __syncthreads();
    } else if (cnt <= 256) {
        // ---- Path B (rare): sort256 (4/lane) + serial NMS ----
        if (wid == 0) {
            u64 v[4];
            #pragma unroll
            for (int r2 = 0; r2 < 4; ++r2) v[r2] = preKey[(lane << 2) | r2];
            for (int k = 2; k <= 256; k <<= 1) {
                for (int j = k >> 1; j > 0; j >>= 1) {
                    if (j >= 4) {
                        int lj = j >> 2;
                        #pragma unroll
                        for (int r2 = 0; r2 < 4; ++r2) {
                            u64 o = __shfl_xor(v[r2], lj, 64);
                            int e = (lane << 2) | r2;
                            bool up = ((e & k) == 0);
                            bool lower = ((lane & lj) == 0);
                            u64 mx = (v[r2] > o) ? v[r2] : o;
                            u64 mn = (v[r2] > o) ? o : v[r2];
                            v[r2] = (up == lower) ? mx : mn;
                        }
                    } else {
                        #pragma unroll
                        for (int r2 = 0; r2 < 4; ++r2) {
                            if ((r2 & j) == 0) {
                                int e = (lane << 2) | r2;
                                bool up = ((e & k) == 0);
                                u64 a = v[r2], c2 = v[r2 | j];
                                if (up ? (a < c2) : (a > c2)) { v[r2] = c2; v[r2 | j] = a; }
                            }
                        }
                    }
                }
            }
            #pragma unroll
            for (int r2 = 0; r2 < 4; ++r2) {
                int e = (lane << 2) | r2;
                if ((unsigned int)(v[r2] >> 32) != 0u) {
                    int idx = 4095 - (int)(v[r2] & 0xFFFFFFFFu);
                    candBox[e] = preBox[posMap[idx]];
                }
            }

            float kx1 = 0.f, ky1 = 0.f, kx2 = 0.f, ky2 = 0.f, karea = 0.f;
            int nk = 0;
            if (cnt > 0 && nf > 0) {
                float4 c = candBox[0];
                for (int r = 0; r < cnt; ) {
                    float4 nx = candBox[r + 1];
                    float carea = (c.z - c.x) * (c.w - c.y);
                    float xx1 = fmaxf(kx1, c.x);
                    float yy1 = fmaxf(ky1, c.y);
                    float xx2 = fminf(kx2, c.z);
                    float yy2 = fminf(ky2, c.w);
                    float inter = fmaxf(xx2 - xx1, 0.f) * fmaxf(yy2 - yy1, 0.f);
                    float iou = inter / ((karea + carea) - inter + 1e-9f);
                    bool sup = (lane < nk) && (iou > NMSTHR);
                    if (__ballot(sup) == 0ULL) {
                        if (lane == nk) {
                            kx1 = c.x; ky1 = c.y; kx2 = c.z; ky2 = c.w; karea = carea;
                            *(float4*)(out + box_base + (size_t)nk * 4) = c;
                        }
                        ++nk;
                        if (nk >= nf) break;
                    }
                    c = nx; ++r;
                }
            }
            if (lane < MAXF) {
                if (lane >= nk)
                    *(float4*)(out + box_base + (size_t)lane * 4) =
                        make_float4(0.f, 0.f, 0.f, 0.f);
                out[mask_off + (size_t)b * MAXF + lane] = (lane < nk) ? 1.0f : 0.0f;
            }
            if (lane == 0) {
                out[cnt_off + b] = (float)nk;
                status_s = (nk < nf) ? 1 : 0;
            }
        }
        __syncthreads();
    } else {
        if (tid == 0) status_s = 1;
        __syncthreads();
    }

    // ---- Path C (correctness-only fallback): full extract-max NMS ----
    if (status_s) {
        if (wid == 0) {
            consumed[lane] = 0ULL;
            __asm__ volatile("s_waitcnt lgkmcnt(0)" ::: "memory");
            float kx1 = 0.f, ky1 = 0.f, kx2 = 0.f, ky2 = 0.f, karea = 0.f;
            int nk = 0;
            while (nk < nf) {
                u64 best = 0ULL;
                for (int w = 0; w < 64; ++w) {
                    int e = (w << 6) | lane;
                    if (e < NN && !((consumed[e >> 6] >> (e & 63)) & 1ULL)) {
                        float s = sc[e];
                        float4 r = rb4[e];
                        float x1 = fminf(r.x, r.z) * W;
                        float x2 = fmaxf(r.x, r.z) * W;
                        float y1 = fminf(r.y, r.w) * H;
                        float y2 = fmaxf(r.y, r.w) * H;
                        if (((y2 - y1) > 0.1f * H) && ((x2 - x1) > 0.1f * W)) {
                            u64 kk = ((u64)(__float_as_uint(s) + 1u) << 32)
                                   | (unsigned int)(4095 - e);
                            if (kk > best) best = kk;
                        }
                    }
                }
                #pragma unroll
                for (int d = 1; d < 64; d <<= 1) {
                    u64 o = __shfl_xor(best, d, 64);
                    if (o > best) best = o;
                }
                if (best == 0ULL) break;
                int idx = 4095 - (int)(best & 0xFFFFFFFFu);
                if (lane == 0) consumed[idx >> 6] |= 1ULL << (idx & 63);
                __asm__ volatile("s_waitcnt lgkmcnt(0)" ::: "memory");
                float4 r = rb4[idx];
                float cx1 = fminf(r.x, r.z) * W;
                float cx2 = fmaxf(r.x, r.z) * W;
                float cy1 = fminf(r.y, r.w) * H;
                float cy2 = fmaxf(r.y, r.w) * H;
                float carea = (cx2 - cx1) * (cy2 - cy1);
                float xx1 = fmaxf(kx1, cx1);
                float yy1 = fmaxf(ky1, cy1);
                float xx2 = fminf(kx2, cx2);
                float yy2 = fminf(ky2, cy2);
                float inter = fmaxf(xx2 - xx1, 0.f) * fmaxf(yy2 - yy1, 0.f);
                float iou = inter / ((karea + carea) - inter + 1e-9f);
                bool sup = (lane < nk) && (iou > NMSTHR);
                if (__ballot(sup) == 0ULL) {
                    if (lane == nk) {
                        kx1 = cx1; ky1 = cy1; kx2 = cx2; ky2 = cy2; karea = carea;
                        *(float4*)(out + box_base + (size_t)nk * 4) =
                            make_float4(cx1, cy1, cx2, cy2);
                    }
                    ++nk;
                }
            }
            if (lane < MAXF) {
                if (lane >= nk)
                    *(float4*)(out + box_base + (size_t)lane * 4) =
                        make_float4(0.f, 0.f, 0.f, 0.f);
                out[mask_off + (size_t)b * MAXF + lane] = (lane < nk) ? 1.0f : 0.0f;
            }
            if (lane == 0)
                out[cnt_off + b] = (float)nk;
        }
    }
}

extern "C" void kernel_launch(void* const* d_in, const int* in_sizes, int n_in,
                              void* d_out, int out_size, void* d_ws, size_t ws_size,
                              hipStream_t stream) {
    const float* rb     = (const float*)d_in[0];
    const float* scores = (const float*)d_in[1];
    const int*   numf   = (const int*)d_in[2];
    const int*   hw     = (const int*)d_in[3];
    const int B = in_sizes[2];              // 8
    const int N = in_sizes[1] / B;          // 4000
    randbox_kernel<<<B, THREADS, 0, stream>>>(rb, scores, numf, hw,
                                              (float*)d_out, N, B);
}

// Round 5
// 19.791 us; speedup vs baseline: 3.7367x; 1.0727x over previous
//
#include <hip/hip_runtime.h>
#include <stdint.h>

#define THREADS 1024
#define MAXF 50
#define PREMAX 256      // Path B limit (rare)
#define FASTMAX 128     // Path A limit (typical cnt ~ 92 +- 9.5)
#define CUT 0.965f      // score prefilter; exactness via nk<nf fallback
#define NMSTHR 0.7f

typedef unsigned long long u64;

__global__ __launch_bounds__(THREADS) void randbox_kernel(
    const float* __restrict__ rb,      // [B, N, 4]
    const float* __restrict__ scores,  // [B, N]
    const int*   __restrict__ numf,    // [B]
    const int*   __restrict__ hw,      // [B, 2] (H, W)
    float* __restrict__ out,           // boxes [B,50,4] | mask [B,50] | count [B]
    int N, int B)
{
    __shared__ u64 preKey[PREMAX];         // (score_bits+1)<<32 | (4095-i); 0=empty
    __shared__ float4 preBox[PREMAX];      // scaled boxes by push slot
    __shared__ float4 candBox[PREMAX + 4]; // boxes in sorted (descending) order
    __shared__ u64 adjRow[FASTMAX][2];     // IoU>thr adjacency (j>i only)
    __shared__ u64 consumed[64];
    __shared__ unsigned int preCnt;
    __shared__ int status_s;

    const int b = blockIdx.x, tid = threadIdx.x, lane = tid & 63, wid = tid >> 6;
    const float H = (float)hw[b * 2 + 0];
    const float W = (float)hw[b * 2 + 1];
    const int nf = numf[b];
    const int NN = (N < 4096) ? N : 4096;
    const float4* rb4 = (const float4*)rb + (size_t)b * N;
    const float*  sc  = scores + (size_t)b * N;

    const size_t box_base = (size_t)b * MAXF * 4;
    const size_t mask_off = (size_t)B * MAXF * 4;
    const size_t cnt_off  = mask_off + (size_t)B * MAXF;

    // ---- Phase 1: batched load, order corners, scale, validity, prefilter ----
    for (int i = tid; i < PREMAX; i += THREADS) preKey[i] = 0ULL;
    if (tid == 0) { preCnt = 0; status_s = 0; }
    __syncthreads();

    {
        float4 rr[4]; float ss[4];
        #pragma unroll
        for (int u = 0; u < 4; ++u) {           // all 8 loads issue back-to-back
            int i = tid + u * THREADS;
            int ic = (i < NN) ? i : 0;
            rr[u] = rb4[ic];
            ss[u] = sc[ic];
        }
        #pragma unroll
        for (int u = 0; u < 4; ++u) {
            int i = tid + u * THREADS;
            if (i < NN) {
                float x1 = fminf(rr[u].x, rr[u].z) * W;
                float x2 = fmaxf(rr[u].x, rr[u].z) * W;
                float y1 = fminf(rr[u].y, rr[u].w) * H;
                float y2 = fmaxf(rr[u].y, rr[u].w) * H;
                bool valid = ((y2 - y1) > 0.1f * H) && ((x2 - x1) > 0.1f * W);
                if (valid && ss[u] > CUT) {
                    unsigned int pos = atomicAdd(&preCnt, 1u);
                    if (pos < PREMAX) {
                        preKey[pos] = ((u64)(__float_as_uint(ss[u]) + 1u) << 32)
                                    | (unsigned int)(4095 - i);
                        preBox[pos] = make_float4(x1, y1, x2, y2);
                    }
                }
            }
        }
    }
    __syncthreads();

    const int cnt = (int)preCnt;

    if (cnt <= FASTMAX) {
        // ---- Path A: rank sort (parallel), ballot adjacency, register greedy ----
        if (tid < FASTMAX) {
            u64 mykey = preKey[tid];
            const ulonglong2* pk2 = (const ulonglong2*)preKey;
            int rank = 0;
            #pragma unroll 8
            for (int j = 0; j < FASTMAX / 2; ++j) {
                ulonglong2 kk = pk2[j];
                rank += (kk.x > mykey) ? 1 : 0;
                rank += (kk.y > mykey) ? 1 : 0;
            }
            if (tid < cnt) candBox[rank] = preBox[tid];  // keys unique -> permutation
        }
        __syncthreads();

        // adjacency: wave w does rows w, w+16, ...; per-lane column boxes cached
        {
            float4 bj0 = candBox[lane];
            float4 bj1 = candBox[64 + lane];
            float aj0 = (bj0.z - bj0.x) * (bj0.w - bj0.y);
            float aj1 = (bj1.z - bj1.x) * (bj1.w - bj1.y);
            for (int i = wid; i < cnt; i += 16) {
                float4 bi = candBox[i];
                float ai = (bi.z - bi.x) * (bi.w - bi.y);
                bool p0 = false, p1 = false;
                if (lane > i && lane < cnt) {
                    float xx1 = fmaxf(bi.x, bj0.x), yy1 = fmaxf(bi.y, bj0.y);
                    float xx2 = fminf(bi.z, bj0.z), yy2 = fminf(bi.w, bj0.w);
                    float inter = fmaxf(xx2 - xx1, 0.f) * fmaxf(yy2 - yy1, 0.f);
                    p0 = inter / ((ai + aj0) - inter + 1e-9f) > NMSTHR;
                }
                int j1 = 64 + lane;
                if (j1 > i && j1 < cnt) {
                    float xx1 = fmaxf(bi.x, bj1.x), yy1 = fmaxf(bi.y, bj1.y);
                    float xx2 = fminf(bi.z, bj1.z), yy2 = fminf(bi.w, bj1.w);
                    float inter = fmaxf(xx2 - xx1, 0.f) * fmaxf(yy2 - yy1, 0.f);
                    p1 = inter / ((ai + aj1) - inter + 1e-9f) > NMSTHR;
                }
                u64 m0 = __ballot(p0);
                u64 m1 = __ballot(p1);
                if (lane == 0) { adjRow[i][0] = m0; adjRow[i][1] = m1; }
            }
        }
        __syncthreads();

        if (wid == 0) {
            // rows in registers: lane l holds rows l and 64+l
            int l2 = 64 + lane;
            u64 r00 = (lane < cnt) ? adjRow[lane][0] : 0ULL;
            u64 r01 = (lane < cnt) ? adjRow[lane][1] : 0ULL;
            u64 r10 = (l2 < cnt) ? adjRow[l2][0] : 0ULL;
            u64 r11 = (l2 < cnt) ? adjRow[l2][1] : 0ULL;

            u64 rem0 = (cnt >= 64) ? ~0ULL : ((cnt > 0) ? ((1ULL << cnt) - 1ULL) : 0ULL);
            u64 rem1 = (cnt > 64)
                     ? ((cnt >= 128) ? ~0ULL : ((1ULL << (cnt - 64)) - 1ULL)) : 0ULL;
            u64 kept0 = 0, kept1 = 0;
            int nk = 0;
            while (nk < nf) {
                int i;
                if (rem0)      i = __builtin_ctzll(rem0);
                else if (rem1) i = 64 + __builtin_ctzll(rem1);
                else break;
                u64 c0, c1;
                if (i < 64) {
                    c0 = __shfl(r00, i, 64); c1 = __shfl(r01, i, 64);
                    kept0 |= 1ULL << i; rem0 &= ~(1ULL << i);
                } else {
                    c0 = __shfl(r10, i - 64, 64); c1 = __shfl(r11, i - 64, 64);
                    kept1 |= 1ULL << (i - 64); rem1 &= ~(1ULL << (i - 64));
                }
                ++nk;
                rem0 &= ~c0; rem1 &= ~c1;
            }

            // epilogue: zero-fill + mask + popcount-rank scatter of kept boxes
            if (lane < MAXF) {
                if (lane >= nk)
                    *(float4*)(out + box_base + (size_t)lane * 4) =
                        make_float4(0.f, 0.f, 0.f, 0.f);
                out[mask_off + (size_t)b * MAXF + lane] = (lane < nk) ? 1.0f : 0.0f;
            }
            u64 below = (1ULL << lane) - 1ULL;
            if ((kept0 >> lane) & 1ULL) {
                int rank = __popcll(kept0 & below);
                *(float4*)(out + box_base + (size_t)rank * 4) = candBox[lane];
            }
            if ((kept1 >> lane) & 1ULL) {
                int rank = __popcll(kept0) + __popcll(kept1 & below);
                *(float4*)(out + box_base + (size_t)rank * 4) = candBox[64 + lane];
            }
            if (lane == 0) {
                out[cnt_off + b] = (float)nk;
                status_s = (nk < nf) ? 1 : 0;
            }
        }
        __syncthreads();
    } else if (cnt <= PREMAX) {
        // ---- Path B (rare): rank sort over 256, serial wave-0 NMS ----
        if (tid < PREMAX) {
            u64 mykey = preKey[tid];
            const ulonglong2* pk2 = (const ulonglong2*)preKey;
            int rank = 0;
            #pragma unroll 8
            for (int j = 0; j < PREMAX / 2; ++j) {
                ulonglong2 kk = pk2[j];
                rank += (kk.x > mykey) ? 1 : 0;
                rank += (kk.y > mykey) ? 1 : 0;
            }
            if (tid < cnt) candBox[rank] = preBox[tid];
        }
        __syncthreads();

        if (wid == 0) {
            float kx1 = 0.f, ky1 = 0.f, kx2 = 0.f, ky2 = 0.f, karea = 0.f;
            int nk = 0;
            if (cnt > 0 && nf > 0) {
                float4 c = candBox[0];
                for (int r = 0; r < cnt; ) {
                    float4 nx = candBox[r + 1];
                    float carea = (c.z - c.x) * (c.w - c.y);
                    float xx1 = fmaxf(kx1, c.x);
                    float yy1 = fmaxf(ky1, c.y);
                    float xx2 = fminf(kx2, c.z);
                    float yy2 = fminf(ky2, c.w);
                    float inter = fmaxf(xx2 - xx1, 0.f) * fmaxf(yy2 - yy1, 0.f);
                    float iou = inter / ((karea + carea) - inter + 1e-9f);
                    bool sup = (lane < nk) && (iou > NMSTHR);
                    if (__ballot(sup) == 0ULL) {
                        if (lane == nk) {
                            kx1 = c.x; ky1 = c.y; kx2 = c.z; ky2 = c.w; karea = carea;
                            *(float4*)(out + box_base + (size_t)nk * 4) = c;
                        }
                        ++nk;
                        if (nk >= nf) break;
                    }
                    c = nx; ++r;
                }
            }
            if (lane < MAXF) {
                if (lane >= nk)
                    *(float4*)(out + box_base + (size_t)lane * 4) =
                        make_float4(0.f, 0.f, 0.f, 0.f);
                out[mask_off + (size_t)b * MAXF + lane] = (lane < nk) ? 1.0f : 0.0f;
            }
            if (lane == 0) {
                out[cnt_off + b] = (float)nk;
                status_s = (nk < nf) ? 1 : 0;
            }
        }
        __syncthreads();
    } else {
        if (tid == 0) status_s = 1;
        __syncthreads();
    }

    // ---- Path C (correctness-only fallback): full extract-max NMS ----
    if (status_s) {
        if (wid == 0) {
            consumed[lane] = 0ULL;
            __asm__ volatile("s_waitcnt lgkmcnt(0)" ::: "memory");
            float kx1 = 0.f, ky1 = 0.f, kx2 = 0.f, ky2 = 0.f, karea = 0.f;
            int nk = 0;
            while (nk < nf) {
                u64 best = 0ULL;
                for (int w = 0; w < 64; ++w) {
                    int e = (w << 6) | lane;
                    if (e < NN && !((consumed[e >> 6] >> (e & 63)) & 1ULL)) {
                        float s = sc[e];
                        float4 r = rb4[e];
                        float x1 = fminf(r.x, r.z) * W;
                        float x2 = fmaxf(r.x, r.z) * W;
                        float y1 = fminf(r.y, r.w) * H;
                        float y2 = fmaxf(r.y, r.w) * H;
                        if (((y2 - y1) > 0.1f * H) && ((x2 - x1) > 0.1f * W)) {
                            u64 kk = ((u64)(__float_as_uint(s) + 1u) << 32)
                                   | (unsigned int)(4095 - e);
                            if (kk > best) best = kk;
                        }
                    }
                }
                #pragma unroll
                for (int d = 1; d < 64; d <<= 1) {
                    u64 o = __shfl_xor(best, d, 64);
                    if (o > best) best = o;
                }
                if (best == 0ULL) break;
                int idx = 4095 - (int)(best & 0xFFFFFFFFu);
                if (lane == 0) consumed[idx >> 6] |= 1ULL << (idx & 63);
                __asm__ volatile("s_waitcnt lgkmcnt(0)" ::: "memory");
                float4 r = rb4[idx];
                float cx1 = fminf(r.x, r.z) * W;
                float cx2 = fmaxf(r.x, r.z) * W;
                float cy1 = fminf(r.y, r.w) * H;
                float cy2 = fmaxf(r.y, r.w) * H;
                float carea = (cx2 - cx1) * (cy2 - cy1);
                float xx1 = fmaxf(kx1, cx1);
                float yy1 = fmaxf(ky1, cy1);
                float xx2 = fminf(kx2, cx2);
                float yy2 = fminf(ky2, cy2);
                float inter = fmaxf(xx2 - xx1, 0.f) * fmaxf(yy2 - yy1, 0.f);
                float iou = inter / ((karea + carea) - inter + 1e-9f);
                bool sup = (lane < nk) && (iou > NMSTHR);
                if (__ballot(sup) == 0ULL) {
                    if (lane == nk) {
                        kx1 = cx1; ky1 = cy1; kx2 = cx2; ky2 = cy2; karea = carea;
                        *(float4*)(out + box_base + (size_t)nk * 4) =
                            make_float4(cx1, cy1, cx2, cy2);
                    }
                    ++nk;
                }
            }
            if (lane < MAXF) {
                if (lane >= nk)
                    *(float4*)(out + box_base + (size_t)lane * 4) =
                        make_float4(0.f, 0.f, 0.f, 0.f);
                out[mask_off + (size_t)b * MAXF + lane] = (lane < nk) ? 1.0f : 0.0f;
            }
            if (lane == 0)
                out[cnt_off + b] = (float)nk;
        }
    }
}

extern "C" void kernel_launch(void* const* d_in, const int* in_sizes, int n_in,
                              void* d_out, int out_size, void* d_ws, size_t ws_size,
                              hipStream_t stream) {
    const float* rb     = (const float*)d_in[0];
    const float* scores = (const float*)d_in[1];
    const int*   numf   = (const int*)d_in[2];
    const int*   hw     = (const int*)d_in[3];
    const int B = in_sizes[2];              // 8
    const int N = in_sizes[1] / B;          // 4000
    randbox_kernel<<<B, THREADS, 0, stream>>>(rb, scores, numf, hw,
                                              (float*)d_out, N, B);
}

// Round 6
// 17.168 us; speedup vs baseline: 4.3075x; 1.1528x over previous
//
#include <hip/hip_runtime.h>
#include <stdint.h>

#define THREADS 1024
#define MAXF 50
#define PREMAX 256      // Path B limit (rare)
#define FASTMAX 128     // Path A limit (typical cnt ~ 92 +- 9.5)
#define CUT 0.965f      // score prefilter; exactness via nk<nf fallback
#define NMSTHR 0.7f

typedef unsigned long long u64;

__global__ __launch_bounds__(THREADS) void randbox_kernel(
    const float* __restrict__ rb,      // [B, N, 4]
    const float* __restrict__ scores,  // [B, N]
    const int*   __restrict__ numf,    // [B]
    const int*   __restrict__ hw,      // [B, 2] (H, W)
    float* __restrict__ out,           // boxes [B,50,4] | mask [B,50] | count [B]
    int N, int B)
{
    __shared__ u64 preKey[PREMAX];         // (score_bits+1)<<32 | (4095-i); 0=empty
    __shared__ float4 preBox[PREMAX];      // scaled boxes by push slot
    __shared__ float4 candBox[PREMAX + 4]; // boxes in sorted (descending) order
    __shared__ u64 colLds[FASTMAX][2];     // COLUMN-major adjacency: col c, rows 0-63 / 64-127
    __shared__ u64 consumed[64];
    __shared__ unsigned int preCnt;
    __shared__ int status_s;

    const int b = blockIdx.x, tid = threadIdx.x, lane = tid & 63, wid = tid >> 6;
    const float H = (float)hw[b * 2 + 0];
    const float W = (float)hw[b * 2 + 1];
    const int nf = numf[b];
    const int NN = (N < 4096) ? N : 4096;
    const float4* rb4 = (const float4*)rb + (size_t)b * N;
    const float*  sc  = scores + (size_t)b * N;

    const size_t box_base = (size_t)b * MAXF * 4;
    const size_t mask_off = (size_t)B * MAXF * 4;
    const size_t cnt_off  = mask_off + (size_t)B * MAXF;

    // ---- Phase 1: batched load, order corners, scale, validity, prefilter ----
    for (int i = tid; i < PREMAX; i += THREADS) preKey[i] = 0ULL;
    if (tid == 0) { preCnt = 0; status_s = 0; }
    __syncthreads();

    {
        float4 rr[4]; float ss[4];
        #pragma unroll
        for (int u = 0; u < 4; ++u) {           // all 8 loads issue back-to-back
            int i = tid + u * THREADS;
            int ic = (i < NN) ? i : 0;
            rr[u] = rb4[ic];
            ss[u] = sc[ic];
        }
        #pragma unroll
        for (int u = 0; u < 4; ++u) {
            int i = tid + u * THREADS;
            if (i < NN) {
                float x1 = fminf(rr[u].x, rr[u].z) * W;
                float x2 = fmaxf(rr[u].x, rr[u].z) * W;
                float y1 = fminf(rr[u].y, rr[u].w) * H;
                float y2 = fmaxf(rr[u].y, rr[u].w) * H;
                bool valid = ((y2 - y1) > 0.1f * H) && ((x2 - x1) > 0.1f * W);
                if (valid && ss[u] > CUT) {
                    unsigned int pos = atomicAdd(&preCnt, 1u);
                    if (pos < PREMAX) {
                        preKey[pos] = ((u64)(__float_as_uint(ss[u]) + 1u) << 32)
                                    | (unsigned int)(4095 - i);
                        preBox[pos] = make_float4(x1, y1, x2, y2);
                    }
                }
            }
        }
    }
    __syncthreads();

    const int cnt = (int)preCnt;

    if (cnt <= FASTMAX) {
        // ---- Path A: rank sort, column-ballot adjacency, ballot greedy ----
        if (tid < FASTMAX) {
            u64 mykey = preKey[tid];
            const ulonglong2* pk2 = (const ulonglong2*)preKey;
            int nb = (cnt + 1) >> 1;
            int rank = 0;
            #pragma unroll 4
            for (int j = 0; j < nb; ++j) {
                ulonglong2 kk = pk2[j];
                rank += (kk.x > mykey) ? 1 : 0;
                rank += (kk.y > mykey) ? 1 : 0;
            }
            if (tid < cnt) candBox[rank] = preBox[tid];  // keys unique -> permutation
        }
        __syncthreads();

        // column-major adjacency: wave w does cols c = w, w+16, ...
        // ballot lane = ROW index; strict upper triangle (row < col).
        {
            float4 bj0 = candBox[lane];          // row 'lane'
            float4 bj1 = candBox[64 + lane];     // row 'lane+64'
            float aj0 = (bj0.z - bj0.x) * (bj0.w - bj0.y);
            float aj1 = (bj1.z - bj1.x) * (bj1.w - bj1.y);
            for (int c = wid; c < cnt; c += 16) {
                float4 bc = candBox[c];
                float ac = (bc.z - bc.x) * (bc.w - bc.y);
                bool p0 = false, p1 = false;
                if (lane < c) {
                    float xx1 = fmaxf(bc.x, bj0.x), yy1 = fmaxf(bc.y, bj0.y);
                    float xx2 = fminf(bc.z, bj0.z), yy2 = fminf(bc.w, bj0.w);
                    float inter = fmaxf(xx2 - xx1, 0.f) * fmaxf(yy2 - yy1, 0.f);
                    p0 = inter / ((ac + aj0) - inter + 1e-9f) > NMSTHR;
                }
                int i1 = 64 + lane;
                if (i1 < c) {
                    float xx1 = fmaxf(bc.x, bj1.x), yy1 = fmaxf(bc.y, bj1.y);
                    float xx2 = fminf(bc.z, bj1.z), yy2 = fminf(bc.w, bj1.w);
                    float inter = fmaxf(xx2 - xx1, 0.f) * fmaxf(yy2 - yy1, 0.f);
                    p1 = inter / ((ac + aj1) - inter + 1e-9f) > NMSTHR;
                }
                u64 m0 = __ballot(p0);
                u64 m1 = __ballot(p1);
                if (lane == 0) { colLds[c][0] = m0; colLds[c][1] = m1; }
            }
        }
        __syncthreads();

        if (wid == 0) {
            // lane j holds columns j and j+64 (each 128 rows = 2 words)
            u64 cA0 = colLds[lane][0],      cA1 = colLds[lane][1];
            u64 cB0 = colLds[64 + lane][0], cB1 = colLds[64 + lane][1];

            u64 rem0 = (cnt >= 64) ? ~0ULL : ((cnt > 0) ? ((1ULL << cnt) - 1ULL) : 0ULL);
            u64 rem1 = (cnt > 64)
                     ? ((cnt >= 128) ? ~0ULL : ((1ULL << (cnt - 64)) - 1ULL)) : 0ULL;
            u64 kept0 = 0, kept1 = 0;
            int nk = 0;
            while (nk < nf) {
                int i;
                if (rem0)      i = __builtin_ctzll(rem0);
                else if (rem1) i = 64 + __builtin_ctzll(rem1);
                else break;
                u64 supLo, supHi;
                if (i < 64) {
                    supLo = __ballot(((cA0 >> i) & 1ULL) != 0ULL);  // cols 0-63 hit by row i
                    supHi = __ballot(((cB0 >> i) & 1ULL) != 0ULL);  // cols 64-127
                    kept0 |= 1ULL << i;  rem0 &= ~(1ULL << i);
                } else {
                    int s = i - 64;
                    supLo = __ballot(((cA1 >> s) & 1ULL) != 0ULL);
                    supHi = __ballot(((cB1 >> s) & 1ULL) != 0ULL);
                    kept1 |= 1ULL << s;  rem1 &= ~(1ULL << s);
                }
                ++nk;
                rem0 &= ~supLo;  rem1 &= ~supHi;
            }

            // epilogue: zero-fill + mask + popcount-rank scatter of kept boxes
            if (lane < MAXF) {
                if (lane >= nk)
                    *(float4*)(out + box_base + (size_t)lane * 4) =
                        make_float4(0.f, 0.f, 0.f, 0.f);
                out[mask_off + (size_t)b * MAXF + lane] = (lane < nk) ? 1.0f : 0.0f;
            }
            u64 below = (1ULL << lane) - 1ULL;
            if ((kept0 >> lane) & 1ULL) {
                int rank = __popcll(kept0 & below);
                *(float4*)(out + box_base + (size_t)rank * 4) = candBox[lane];
            }
            if ((kept1 >> lane) & 1ULL) {
                int rank = __popcll(kept0) + __popcll(kept1 & below);
                *(float4*)(out + box_base + (size_t)rank * 4) = candBox[64 + lane];
            }
            if (lane == 0) {
                out[cnt_off + b] = (float)nk;
                status_s = (nk < nf) ? 1 : 0;
            }
        }
        __syncthreads();
    } else if (cnt <= PREMAX) {
        // ---- Path B (rare): rank sort over 256, serial wave-0 NMS ----
        if (tid < PREMAX) {
            u64 mykey = preKey[tid];
            const ulonglong2* pk2 = (const ulonglong2*)preKey;
            int rank = 0;
            #pragma unroll 8
            for (int j = 0; j < PREMAX / 2; ++j) {
                ulonglong2 kk = pk2[j];
                rank += (kk.x > mykey) ? 1 : 0;
                rank += (kk.y > mykey) ? 1 : 0;
            }
            if (tid < cnt) candBox[rank] = preBox[tid];
        }
        __syncthreads();

        if (wid == 0) {
            float kx1 = 0.f, ky1 = 0.f, kx2 = 0.f, ky2 = 0.f, karea = 0.f;
            int nk = 0;
            if (cnt > 0 && nf > 0) {
                float4 c = candBox[0];
                for (int r = 0; r < cnt; ) {
                    float4 nx = candBox[r + 1];
                    float carea = (c.z - c.x) * (c.w - c.y);
                    float xx1 = fmaxf(kx1, c.x);
                    float yy1 = fmaxf(ky1, c.y);
                    float xx2 = fminf(kx2, c.z);
                    float yy2 = fminf(ky2, c.w);
                    float inter = fmaxf(xx2 - xx1, 0.f) * fmaxf(yy2 - yy1, 0.f);
                    float iou = inter / ((karea + carea) - inter + 1e-9f);
                    bool sup = (lane < nk) && (iou > NMSTHR);
                    if (__ballot(sup) == 0ULL) {
                        if (lane == nk) {
                            kx1 = c.x; ky1 = c.y; kx2 = c.z; ky2 = c.w; karea = carea;
                            *(float4*)(out + box_base + (size_t)nk * 4) = c;
                        }
                        ++nk;
                        if (nk >= nf) break;
                    }
                    c = nx; ++r;
                }
            }
            if (lane < MAXF) {
                if (lane >= nk)
                    *(float4*)(out + box_base + (size_t)lane * 4) =
                        make_float4(0.f, 0.f, 0.f, 0.f);
                out[mask_off + (size_t)b * MAXF + lane] = (lane < nk) ? 1.0f : 0.0f;
            }
            if (lane == 0) {
                out[cnt_off + b] = (float)nk;
                status_s = (nk < nf) ? 1 : 0;
            }
        }
        __syncthreads();
    } else {
        if (tid == 0) status_s = 1;
        __syncthreads();
    }

    // ---- Path C (correctness-only fallback): full extract-max NMS ----
    if (status_s) {
        if (wid == 0) {
            consumed[lane] = 0ULL;
            __asm__ volatile("s_waitcnt lgkmcnt(0)" ::: "memory");
            float kx1 = 0.f, ky1 = 0.f, kx2 = 0.f, ky2 = 0.f, karea = 0.f;
            int nk = 0;
            while (nk < nf) {
                u64 best = 0ULL;
                for (int w = 0; w < 64; ++w) {
                    int e = (w << 6) | lane;
                    if (e < NN && !((consumed[e >> 6] >> (e & 63)) & 1ULL)) {
                        float s = sc[e];
                        float4 r = rb4[e];
                        float x1 = fminf(r.x, r.z) * W;
                        float x2 = fmaxf(r.x, r.z) * W;
                        float y1 = fminf(r.y, r.w) * H;
                        float y2 = fmaxf(r.y, r.w) * H;
                        if (((y2 - y1) > 0.1f * H) && ((x2 - x1) > 0.1f * W)) {
                            u64 kk = ((u64)(__float_as_uint(s) + 1u) << 32)
                                   | (unsigned int)(4095 - e);
                            if (kk > best) best = kk;
                        }
                    }
                }
                #pragma unroll
                for (int d = 1; d < 64; d <<= 1) {
                    u64 o = __shfl_xor(best, d, 64);
                    if (o > best) best = o;
                }
                if (best == 0ULL) break;
                int idx = 4095 - (int)(best & 0xFFFFFFFFu);
                if (lane == 0) consumed[idx >> 6] |= 1ULL << (idx & 63);
                __asm__ volatile("s_waitcnt lgkmcnt(0)" ::: "memory");
                float4 r = rb4[idx];
                float cx1 = fminf(r.x, r.z) * W;
                float cx2 = fmaxf(r.x, r.z) * W;
                float cy1 = fminf(r.y, r.w) * H;
                float cy2 = fmaxf(r.y, r.w) * H;
                float carea = (cx2 - cx1) * (cy2 - cy1);
                float xx1 = fmaxf(kx1, cx1);
                float yy1 = fmaxf(ky1, cy1);
                float xx2 = fminf(kx2, cx2);
                float yy2 = fminf(ky2, cy2);
                float inter = fmaxf(xx2 - xx1, 0.f) * fmaxf(yy2 - yy1, 0.f);
                float iou = inter / ((karea + carea) - inter + 1e-9f);
                bool sup = (lane < nk) && (iou > NMSTHR);
                if (__ballot(sup) == 0ULL) {
                    if (lane == nk) {
                        kx1 = cx1; ky1 = cy1; kx2 = cx2; ky2 = cy2; karea = carea;
                        *(float4*)(out + box_base + (size_t)nk * 4) =
                            make_float4(cx1, cy1, cx2, cy2);
                    }
                    ++nk;
                }
            }
            if (lane < MAXF) {
                if (lane >= nk)
                    *(float4*)(out + box_base + (size_t)lane * 4) =
                        make_float4(0.f, 0.f, 0.f, 0.f);
                out[mask_off + (size_t)b * MAXF + lane] = (lane < nk) ? 1.0f : 0.0f;
            }
            if (lane == 0)
                out[cnt_off + b] = (float)nk;
        }
    }
}

extern "C" void kernel_launch(void* const* d_in, const int* in_sizes, int n_in,
                              void* d_out, int out_size, void* d_ws, size_t ws_size,
                              hipStream_t stream) {
    const float* rb     = (const float*)d_in[0];
    const float* scores = (const float*)d_in[1];
    const int*   numf   = (const int*)d_in[2];
    const int*   hw     = (const int*)d_in[3];
    const int B = in_sizes[2];              // 8
    const int N = in_sizes[1] / B;          // 4000
    randbox_kernel<<<B, THREADS, 0, stream>>>(rb, scores, numf, hw,
                                              (float*)d_out, N, B);
}

// Round 7
// 17.165 us; speedup vs baseline: 4.3082x; 1.0002x over previous
//
#include <hip/hip_runtime.h>
#include <stdint.h>

#define THREADS 1024
#define MAXF 50
#define PREMAX 256      // Path B limit (rare)
#define FASTMAX 128     // Path A limit (typical cnt ~ 92 +- 9.5)
#define CUT 0.965f      // score prefilter; exactness via nk<nf fallback
#define NMSTHR 0.7f

typedef unsigned long long u64;

__global__ __launch_bounds__(THREADS) void randbox_kernel(
    const float* __restrict__ rb,      // [B, N, 4]
    const float* __restrict__ scores,  // [B, N]
    const int*   __restrict__ numf,    // [B]
    const int*   __restrict__ hw,      // [B, 2] (H, W)
    float* __restrict__ out,           // boxes [B,50,4] | mask [B,50] | count [B]
    int N, int B)
{
    __shared__ u64 preKey[PREMAX];         // (score_bits+1)<<32 | (4095-i); 0=empty
    __shared__ float4 preBox[PREMAX];      // scaled boxes by push slot
    __shared__ float4 candBox[PREMAX + 4]; // boxes in sorted (descending) order
    __shared__ u64 colLds[FASTMAX][2];     // COLUMN-major adjacency
    __shared__ u64 consumed[64];
    __shared__ unsigned int preCnt;
    __shared__ int status_s;

    const int b = blockIdx.x, tid = threadIdx.x, lane = tid & 63, wid = tid >> 6;
    const float H = (float)hw[b * 2 + 0];
    const float W = (float)hw[b * 2 + 1];
    const int nf = numf[b];
    const int NN = (N < 4096) ? N : 4096;
    const float4* rb4 = (const float4*)rb + (size_t)b * N;
    const float*  sc  = scores + (size_t)b * N;

    const size_t box_base = (size_t)b * MAXF * 4;
    const size_t mask_off = (size_t)B * MAXF * 4;
    const size_t cnt_off  = mask_off + (size_t)B * MAXF;

    // ---- Phase 1: score-first load; gather boxes only for score-passing ----
    for (int i = tid; i < PREMAX; i += THREADS) preKey[i] = 0ULL;
    if (tid == 0) { preCnt = 0; status_s = 0; }
    __syncthreads();

    {
        const int i0 = tid << 2;
        float ss[4];
        bool have4 = (i0 + 3 < NN);
        if (have4) {                       // one coalesced 16B score load
            float4 s4 = ((const float4*)sc)[tid];
            ss[0] = s4.x; ss[1] = s4.y; ss[2] = s4.z; ss[3] = s4.w;
        } else {
            #pragma unroll
            for (int u = 0; u < 4; ++u)
                ss[u] = (i0 + u < NN) ? sc[i0 + u] : 0.0f;
        }
        if (i0 < NN) {
            #pragma unroll
            for (int u = 0; u < 4; ++u) {
                int i = i0 + u;
                if (i < NN && ss[u] > CUT) {      // ~3.5% of boxes
                    float4 r = rb4[i];            // dependent gather
                    float x1 = fminf(r.x, r.z) * W;
                    float x2 = fmaxf(r.x, r.z) * W;
                    float y1 = fminf(r.y, r.w) * H;
                    float y2 = fmaxf(r.y, r.w) * H;
                    bool valid = ((y2 - y1) > 0.1f * H) && ((x2 - x1) > 0.1f * W);
                    if (valid) {
                        unsigned int pos = atomicAdd(&preCnt, 1u);
                        if (pos < PREMAX) {
                            preKey[pos] = ((u64)(__float_as_uint(ss[u]) + 1u) << 32)
                                        | (unsigned int)(4095 - i);
                            preBox[pos] = make_float4(x1, y1, x2, y2);
                        }
                    }
                }
            }
        }
    }
    __syncthreads();

    const int cnt = (int)preCnt;

    if (cnt <= FASTMAX) {
        // ---- Path A: rank sort, column-ballot adjacency, ballot greedy ----
        if (tid < FASTMAX) {
            u64 mykey = preKey[tid];
            const ulonglong2* pk2 = (const ulonglong2*)preKey;
            int nb = (cnt + 1) >> 1;
            int rank = 0;
            #pragma unroll 4
            for (int j = 0; j < nb; ++j) {
                ulonglong2 kk = pk2[j];
                rank += (kk.x > mykey) ? 1 : 0;
                rank += (kk.y > mykey) ? 1 : 0;
            }
            if (tid < cnt) candBox[rank] = preBox[tid];  // keys unique -> permutation
        }
        __syncthreads();

        // column-major adjacency: wave w does cols c = w, w+16, ...
        // ballot lane = ROW index; strict upper triangle (row < col).
        {
            float4 bj0 = candBox[lane];          // row 'lane'
            float4 bj1 = candBox[64 + lane];     // row 'lane+64'
            float aj0 = (bj0.z - bj0.x) * (bj0.w - bj0.y);
            float aj1 = (bj1.z - bj1.x) * (bj1.w - bj1.y);
            for (int c = wid; c < cnt; c += 16) {
                float4 bc = candBox[c];
                float ac = (bc.z - bc.x) * (bc.w - bc.y);
                bool p0 = false, p1 = false;
                if (lane < c) {
                    float xx1 = fmaxf(bc.x, bj0.x), yy1 = fmaxf(bc.y, bj0.y);
                    float xx2 = fminf(bc.z, bj0.z), yy2 = fminf(bc.w, bj0.w);
                    float inter = fmaxf(xx2 - xx1, 0.f) * fmaxf(yy2 - yy1, 0.f);
                    p0 = inter / ((ac + aj0) - inter + 1e-9f) > NMSTHR;
                }
                int i1 = 64 + lane;
                if (i1 < c) {
                    float xx1 = fmaxf(bc.x, bj1.x), yy1 = fmaxf(bc.y, bj1.y);
                    float xx2 = fminf(bc.z, bj1.z), yy2 = fminf(bc.w, bj1.w);
                    float inter = fmaxf(xx2 - xx1, 0.f) * fmaxf(yy2 - yy1, 0.f);
                    p1 = inter / ((ac + aj1) - inter + 1e-9f) > NMSTHR;
                }
                u64 m0 = __ballot(p0);
                u64 m1 = __ballot(p1);
                if (lane == 0) { colLds[c][0] = m0; colLds[c][1] = m1; }
            }
        }
        __syncthreads();

        if (wid == 0) {
            // lane j holds columns j and j+64 (each 128 rows = 2 words)
            u64 cA0 = colLds[lane][0],      cA1 = colLds[lane][1];
            u64 cB0 = colLds[64 + lane][0], cB1 = colLds[64 + lane][1];

            u64 rem0 = (cnt >= 64) ? ~0ULL : ((cnt > 0) ? ((1ULL << cnt) - 1ULL) : 0ULL);
            u64 rem1 = (cnt > 64)
                     ? ((cnt >= 128) ? ~0ULL : ((1ULL << (cnt - 64)) - 1ULL)) : 0ULL;
            u64 kept0 = 0, kept1 = 0;
            int nk = 0;
            while (nk < nf) {
                int i;
                if (rem0)      i = __builtin_ctzll(rem0);
                else if (rem1) i = 64 + __builtin_ctzll(rem1);
                else break;
                u64 supLo, supHi;
                if (i < 64) {
                    supLo = __ballot(((cA0 >> i) & 1ULL) != 0ULL);
                    supHi = __ballot(((cB0 >> i) & 1ULL) != 0ULL);
                    kept0 |= 1ULL << i;  rem0 &= ~(1ULL << i);
                } else {
                    int s = i - 64;
                    supLo = __ballot(((cA1 >> s) & 1ULL) != 0ULL);
                    supHi = __ballot(((cB1 >> s) & 1ULL) != 0ULL);
                    kept1 |= 1ULL << s;  rem1 &= ~(1ULL << s);
                }
                ++nk;
                rem0 &= ~supLo;  rem1 &= ~supHi;
            }

            // epilogue: zero-fill + mask + popcount-rank scatter of kept boxes
            if (lane < MAXF) {
                if (lane >= nk)
                    *(float4*)(out + box_base + (size_t)lane * 4) =
                        make_float4(0.f, 0.f, 0.f, 0.f);
                out[mask_off + (size_t)b * MAXF + lane] = (lane < nk) ? 1.0f : 0.0f;
            }
            u64 below = (1ULL << lane) - 1ULL;
            if ((kept0 >> lane) & 1ULL) {
                int rank = __popcll(kept0 & below);
                *(float4*)(out + box_base + (size_t)rank * 4) = candBox[lane];
            }
            if ((kept1 >> lane) & 1ULL) {
                int rank = __popcll(kept0) + __popcll(kept1 & below);
                *(float4*)(out + box_base + (size_t)rank * 4) = candBox[64 + lane];
            }
            if (lane == 0) {
                out[cnt_off + b] = (float)nk;
                status_s = (nk < nf) ? 1 : 0;
            }
        }
        __syncthreads();
    } else if (cnt <= PREMAX) {
        // ---- Path B (rare): rank sort over 256, serial wave-0 NMS ----
        if (tid < PREMAX) {
            u64 mykey = preKey[tid];
            const ulonglong2* pk2 = (const ulonglong2*)preKey;
            int nb = (cnt + 1) >> 1;
            int rank = 0;
            #pragma unroll 4
            for (int j = 0; j < nb; ++j) {
                ulonglong2 kk = pk2[j];
                rank += (kk.x > mykey) ? 1 : 0;
                rank += (kk.y > mykey) ? 1 : 0;
            }
            if (tid < cnt) candBox[rank] = preBox[tid];
        }
        __syncthreads();

        if (wid == 0) {
            float kx1 = 0.f, ky1 = 0.f, kx2 = 0.f, ky2 = 0.f, karea = 0.f;
            int nk = 0;
            if (cnt > 0 && nf > 0) {
                float4 c = candBox[0];
                for (int r = 0; r < cnt; ) {
                    float4 nx = candBox[r + 1];
                    float carea = (c.z - c.x) * (c.w - c.y);
                    float xx1 = fmaxf(kx1, c.x);
                    float yy1 = fmaxf(ky1, c.y);
                    float xx2 = fminf(kx2, c.z);
                    float yy2 = fminf(ky2, c.w);
                    float inter = fmaxf(xx2 - xx1, 0.f) * fmaxf(yy2 - yy1, 0.f);
                    float iou = inter / ((karea + carea) - inter + 1e-9f);
                    bool sup = (lane < nk) && (iou > NMSTHR);
                    if (__ballot(sup) == 0ULL) {
                        if (lane == nk) {
                            kx1 = c.x; ky1 = c.y; kx2 = c.z; ky2 = c.w; karea = carea;
                            *(float4*)(out + box_base + (size_t)nk * 4) = c;
                        }
                        ++nk;
                        if (nk >= nf) break;
                    }
                    c = nx; ++r;
                }
            }
            if (lane < MAXF) {
                if (lane >= nk)
                    *(float4*)(out + box_base + (size_t)lane * 4) =
                        make_float4(0.f, 0.f, 0.f, 0.f);
                out[mask_off + (size_t)b * MAXF + lane] = (lane < nk) ? 1.0f : 0.0f;
            }
            if (lane == 0) {
                out[cnt_off + b] = (float)nk;
                status_s = (nk < nf) ? 1 : 0;
            }
        }
        __syncthreads();
    } else {
        if (tid == 0) status_s = 1;
        __syncthreads();
    }

    // ---- Path C (correctness-only fallback): full extract-max NMS ----
    if (status_s) {
        if (wid == 0) {
            consumed[lane] = 0ULL;
            __asm__ volatile("s_waitcnt lgkmcnt(0)" ::: "memory");
            float kx1 = 0.f, ky1 = 0.f, kx2 = 0.f, ky2 = 0.f, karea = 0.f;
            int nk = 0;
            while (nk < nf) {
                u64 best = 0ULL;
                for (int w = 0; w < 64; ++w) {
                    int e = (w << 6) | lane;
                    if (e < NN && !((consumed[e >> 6] >> (e & 63)) & 1ULL)) {
                        float s = sc[e];
                        float4 r = rb4[e];
                        float x1 = fminf(r.x, r.z) * W;
                        float x2 = fmaxf(r.x, r.z) * W;
                        float y1 = fminf(r.y, r.w) * H;
                        float y2 = fmaxf(r.y, r.w) * H;
                        if (((y2 - y1) > 0.1f * H) && ((x2 - x1) > 0.1f * W)) {
                            u64 kk = ((u64)(__float_as_uint(s) + 1u) << 32)
                                   | (unsigned int)(4095 - e);
                            if (kk > best) best = kk;
                        }
                    }
                }
                #pragma unroll
                for (int d = 1; d < 64; d <<= 1) {
                    u64 o = __shfl_xor(best, d, 64);
                    if (o > best) best = o;
                }
                if (best == 0ULL) break;
                int idx = 4095 - (int)(best & 0xFFFFFFFFu);
                if (lane == 0) consumed[idx >> 6] |= 1ULL << (idx & 63);
                __asm__ volatile("s_waitcnt lgkmcnt(0)" ::: "memory");
                float4 r = rb4[idx];
                float cx1 = fminf(r.x, r.z) * W;
                float cx2 = fmaxf(r.x, r.z) * W;
                float cy1 = fminf(r.y, r.w) * H;
                float cy2 = fmaxf(r.y, r.w) * H;
                float carea = (cx2 - cx1) * (cy2 - cy1);
                float xx1 = fmaxf(kx1, cx1);
                float yy1 = fmaxf(ky1, cy1);
                float xx2 = fminf(kx2, cx2);
                float yy2 = fminf(ky2, cy2);
                float inter = fmaxf(xx2 - xx1, 0.f) * fmaxf(yy2 - yy1, 0.f);
                float iou = inter / ((karea + carea) - inter + 1e-9f);
                bool sup = (lane < nk) && (iou > NMSTHR);
                if (__ballot(sup) == 0ULL) {
                    if (lane == nk) {
                        kx1 = cx1; ky1 = cy1; kx2 = cx2; ky2 = cy2; karea = carea;
                        *(float4*)(out + box_base + (size_t)nk * 4) =
                            make_float4(cx1, cy1, cx2, cy2);
                    }
                    ++nk;
                }
            }
            if (lane < MAXF) {
                if (lane >= nk)
                    *(float4*)(out + box_base + (size_t)lane * 4) =
                        make_float4(0.f, 0.f, 0.f, 0.f);
                out[mask_off + (size_t)b * MAXF + lane] = (lane < nk) ? 1.0f : 0.0f;
            }
            if (lane == 0)
                out[cnt_off + b] = (float)nk;
        }
    }
}

extern "C" void kernel_launch(void* const* d_in, const int* in_sizes, int n_in,
                              void* d_out, int out_size, void* d_ws, size_t ws_size,
                              hipStream_t stream) {
    const float* rb     = (const float*)d_in[0];
    const float* scores = (const float*)d_in[1];
    const int*   numf   = (const int*)d_in[2];
    const int*   hw     = (const int*)d_in[3];
    const int B = in_sizes[2];              // 8
    const int N = in_sizes[1] / B;          // 4000
    randbox_kernel<<<B, THREADS, 0, stream>>>(rb, scores, numf, hw,
                                              (float*)d_out, N, B);
}